// Round 12
// baseline (188.118 us; speedup 1.0000x reference)
//
#include <hip/hip_runtime.h>
#include <hip/hip_bf16.h>
#include <math.h>

#define EPS 1e-5f

typedef __attribute__((ext_vector_type(8))) short bf8_t;   // 8 bf16 = MFMA A/B frag
typedef __attribute__((ext_vector_type(4))) float f4_t;    // MFMA C/D frag

static __device__ __forceinline__ unsigned short f2b(float f) {
    __hip_bfloat16 h = __float2bfloat16(f);
    return *reinterpret_cast<unsigned short*>(&h);
}

// ws layout (bytes):
//   0        : W1B  frag-linear bf16 of W123: idx ((mt*16+ks)*64+lane)*8+j  (196608 B)
//   196608   : W4B  frag-linear bf16 of W4:   idx ((mt*2+ks)*64+lane)*8+j   (65536 B)
//   262144   : bn1s[192], 262912: bn1h[192]
//   263680   : bn2s[512], 265728: bn2h[512]

// ---------------- K0: weight conversion to fragment-linear bf16 + BN folds ----------------
__global__ __launch_bounds__(256) void k0_prep(
    const float* __restrict__ W123, const float* __restrict__ W4,
    const float* __restrict__ b123, const float* __restrict__ g123,
    const float* __restrict__ be123, const float* __restrict__ m123, const float* __restrict__ v123,
    const float* __restrict__ b4, const float* __restrict__ g4,
    const float* __restrict__ be4, const float* __restrict__ m4, const float* __restrict__ v4,
    unsigned short* __restrict__ w1b, unsigned short* __restrict__ w4b,
    float* __restrict__ bn1s, float* __restrict__ bn1h,
    float* __restrict__ bn2s, float* __restrict__ bn2h)
{
    const int bid = blockIdx.x, tid = threadIdx.x;
    if (bid == 64) {
        if (tid < 192) {
            float s = g123[tid] * rsqrtf(v123[tid] + EPS);
            bn1s[tid] = s;
            bn1h[tid] = be123[tid] + (b123[tid] - m123[tid]) * s;
        }
        for (int c = tid; c < 512; c += 256) {
            float s = g4[c] * rsqrtf(v4[c] + EPS);
            bn2s[c] = s;
            bn2h[c] = be4[c] + (b4[c] - m4[c]) * s;
        }
        return;
    }
    const int f = bid * 256 + tid;     // 0..16383
    const float* src;
    unsigned short* dst;
    if (f < 12288) {                   // W123 frags: 12 mtiles x 16 ksteps x 64 lanes
        int mt = f >> 10, ks = (f >> 6) & 15, lane = f & 63;
        int row = mt * 16 + (lane & 15);
        int k0  = ks * 32 + ((lane >> 4) << 3);
        src = W123 + row * 512 + k0;
        dst = w1b + f * 8;
    } else {                           // W4 frags: 32 mtiles x 2 ksteps x 64 lanes
        int f2 = f - 12288;
        int mt = f2 >> 7, ks = (f2 >> 6) & 1, lane = f2 & 63;
        int row = mt * 16 + (lane & 15);
        int k0  = ks * 32 + ((lane >> 4) << 3);
        src = W4 + row * 64 + k0;
        dst = w4b + f2 * 8;
    }
    float4 a = *(const float4*)src;
    float4 b = *(const float4*)(src + 4);
    union { unsigned short u[8]; uint4 v; } o;
    o.u[0]=f2b(a.x); o.u[1]=f2b(a.y); o.u[2]=f2b(a.z); o.u[3]=f2b(a.w);
    o.u[4]=f2b(b.x); o.u[5]=f2b(b.y); o.u[6]=f2b(b.z); o.u[7]=f2b(b.w);
    *(uint4*)dst = o.v;
}

// ---------------- K1: 1 sample/block, 2048 blocks x 256 threads (4 waves) ----------------
// Tiny LDS (~8.9KB, phase-overlaid union) -> 8 blocks/CU = 32 waves/CU.
// P1/P5 are lane-contiguous float4 streams with 8-deep MLP.
__global__ __launch_bounds__(256, 8) void k1_mfma(
    const float* __restrict__ x,
    const unsigned short* __restrict__ w1b,
    const unsigned short* __restrict__ w4b,
    const float* __restrict__ bn1s, const float* __restrict__ bn1h,
    const float* __restrict__ bn2s, const float* __restrict__ bn2h,
    float* __restrict__ out)
{
    // Union region, 8768 B. Time-disjoint overlays:
    //   Bxs  [4][520] bf16 @ 0     (4160B)  live P1 -> GEMM1
    //   actL [192][5] f32  @ 4160  (3840B)  live GEMM1 -> P3b
    //   B2   [4][72]  bf16 @ 0     (576B)   live P3b -> GEMM2 (in dead Bxs space)
    //   bn2L [512][4] f32  @ 576   (8192B)  live GEMM2-epi -> P5 (no overlap with live B2)
    __shared__ __align__(16) char U[8768];
    __shared__ float smx[20];

    unsigned short* Bxs  = (unsigned short*)&U[0];      // [p][c] stride 520
    float*          actL = (float*)&U[4160];            // [row][col] stride 5
    unsigned short* B2   = (unsigned short*)&U[0];      // [l][d] stride 72
    float*          bn2L = (float*)&U[576];             // [c][h] stride 4

    const int tid = threadIdx.x;
    const int lane = tid & 63, w = tid >> 6;
    const int n = blockIdx.x;
    const float4* x4 = (const float4*)(x + (size_t)n * 8192);
    float4* o4 = (float4*)(out + (size_t)n * 8192);

    // ---- P1: stream x (512 float4s per 256 thr x 8), build Bxs (bf16, subsampled)
    #pragma unroll
    for (int k = 0; k < 8; ++k) {
        int f = tid + k * 256;             // float4 index; c = f>>2, j = f&3 (j == h)
        float4 v = x4[f];
        int c = f >> 2, j = f & 3;
        if (j == 0) {                      // floats 0..3: (h0,w0)=.x, (h0,w2)=.z
            Bxs[0 * 520 + c] = f2b(v.x);
            Bxs[1 * 520 + c] = f2b(v.z);
        } else if (j == 2) {               // floats 8..11: (h2,w0)=.x, (h2,w2)=.z
            Bxs[2 * 520 + c] = f2b(v.x);
            Bxs[3 * 520 + c] = f2b(v.z);
        }
    }
    __syncthreads();

    // ---- GEMM1: C1(192x4) = W123(192x512) @ XS(512x4); wave w owns mtiles 3w..3w+2
    {
        f4_t acc[3] = {};
        const bf8_t* Af = (const bf8_t*)w1b;
        const int col = lane & 15, kb = (lane >> 4) << 3;
        for (int ks = 0; ks < 16; ++ks) {
            bf8_t bf = *(const bf8_t*)&Bxs[(col & 3) * 520 + ks * 32 + kb];
            #pragma unroll
            for (int mi = 0; mi < 3; ++mi) {
                int mt = w * 3 + mi;
                bf8_t af = Af[(mt * 16 + ks) * 64 + lane];
                acc[mi] = __builtin_amdgcn_mfma_f32_16x16x32_bf16(af, bf, acc[mi], 0, 0, 0);
            }
        }
        if (col < 4) {
            #pragma unroll
            for (int mi = 0; mi < 3; ++mi) {
                int rbase = (w * 3 + mi) * 16 + ((lane >> 4) << 2);
                #pragma unroll
                for (int r = 0; r < 4; ++r) {
                    int row = rbase + r;
                    float v = acc[mi][r] * bn1s[row] + bn1h[row];
                    actL[row * 5 + col] = fmaxf(v, 0.f);
                }
            }
        }
    }
    __syncthreads();

    // ---- P3a: scores[l][m] = sum_d q[d][l]*k[d][m]  (threads 0..31; 2 lanes per dot)
    if (tid < 32) {
        int l = (tid >> 3) & 3, m = (tid >> 1) & 3, dg = tid & 1;
        float part = 0.f;
        #pragma unroll 8
        for (int kk = 0; kk < 32; ++kk) {
            int d = dg * 32 + kk;
            part += actL[d * 5 + l] * actL[(64 + d) * 5 + m];
        }
        part += __shfl_xor(part, 1);
        if (dg == 0) smx[l * 4 + m] = part;
    }
    __syncthreads();

    // ---- softmax rows (threads 0..3)
    if (tid < 4) {
        int l = tid;
        float s0 = smx[l*4+0], s1 = smx[l*4+1], s2 = smx[l*4+2], s3 = smx[l*4+3];
        float mx = fmaxf(fmaxf(s0, s1), fmaxf(s2, s3));
        float e0 = expf(s0-mx), e1 = expf(s1-mx), e2 = expf(s2-mx), e3 = expf(s3-mx);
        float inv = 1.f / (e0 + e1 + e2 + e3);
        smx[l*4+0] = e0*inv; smx[l*4+1] = e1*inv;
        smx[l*4+2] = e2*inv; smx[l*4+3] = e3*inv;
    }
    __syncthreads();

    // ---- P3b: att[l][d] = sum_m p[l][m]*v[d][m] -> B2 bf16 [l][d]
    if (tid < 32) {
        int l = tid >> 3, d0 = (tid & 7) * 8;
        float p0 = smx[l*4+0], p1 = smx[l*4+1], p2 = smx[l*4+2], p3 = smx[l*4+3];
        #pragma unroll
        for (int j = 0; j < 8; ++j) {
            int d = d0 + j;
            float sum = p0 * actL[(128+d)*5 + 0] + p1 * actL[(128+d)*5 + 1]
                      + p2 * actL[(128+d)*5 + 2] + p3 * actL[(128+d)*5 + 3];
            B2[l * 72 + d] = f2b(sum);
        }
    }
    __syncthreads();

    // ---- GEMM2: C2(512x4) = W4(512x64) @ att(64x4); wave w owns mtiles 8w..8w+7
    {
        const bf8_t* A2f = (const bf8_t*)w4b;
        const int col = lane & 15, kb = (lane >> 4) << 3;
        f4_t acc2[8] = {};
        #pragma unroll
        for (int ks = 0; ks < 2; ++ks) {
            bf8_t bf = *(const bf8_t*)&B2[(col & 3) * 72 + ks * 32 + kb];
            #pragma unroll
            for (int mi = 0; mi < 8; ++mi) {
                int mt = w * 8 + mi;
                bf8_t af = A2f[(mt * 2 + ks) * 64 + lane];
                acc2[mi] = __builtin_amdgcn_mfma_f32_16x16x32_bf16(af, bf, acc2[mi], 0, 0, 0);
            }
        }
        // BN2 -> bn2L[c][h=col] (cols 0-3 real); no overlap with live B2 (bn2L starts @576)
        if (col < 4) {
            #pragma unroll
            for (int mi = 0; mi < 8; ++mi) {
                int cbase = (w * 8 + mi) * 16 + ((lane >> 4) << 2);
                #pragma unroll
                for (int r = 0; r < 4; ++r) {
                    int c = cbase + r;
                    bn2L[c * 4 + col] = acc2[mi][r] * bn2s[c] + bn2h[c];
                }
            }
        }
    }
    __syncthreads();

    // ---- P5: out = x + bn2 (broadcast over w); lane-contiguous float4, 8-deep
    #pragma unroll
    for (int k = 0; k < 8; ++k) {
        int f = tid + k * 256;
        int c = f >> 2, j = f & 3;         // j == h
        float b = bn2L[c * 4 + j];
        float4 v = x4[f];
        o4[f] = make_float4(v.x + b, v.y + b, v.z + b, v.w + b);
    }
}

extern "C" void kernel_launch(void* const* d_in, const int* in_sizes, int n_in,
                              void* d_out, int out_size, void* d_ws, size_t ws_size,
                              hipStream_t stream) {
    const float* x     = (const float*)d_in[0];
    const float* W123  = (const float*)d_in[1];
    const float* b123  = (const float*)d_in[2];
    const float* g123  = (const float*)d_in[3];
    const float* be123 = (const float*)d_in[4];
    const float* m123  = (const float*)d_in[5];
    const float* v123  = (const float*)d_in[6];
    const float* W4    = (const float*)d_in[7];
    const float* b4    = (const float*)d_in[8];
    const float* g4    = (const float*)d_in[9];
    const float* be4   = (const float*)d_in[10];
    const float* m4    = (const float*)d_in[11];
    const float* v4    = (const float*)d_in[12];
    float* outp = (float*)d_out;

    char* ws = (char*)d_ws;
    unsigned short* w1b = (unsigned short*)ws;
    unsigned short* w4b = (unsigned short*)(ws + 196608);
    float* bn1s = (float*)(ws + 262144);
    float* bn1h = (float*)(ws + 262912);
    float* bn2s = (float*)(ws + 263680);
    float* bn2h = (float*)(ws + 265728);

    k0_prep<<<65, 256, 0, stream>>>(W123, W4, b123, g123, be123, m123, v123,
                                    b4, g4, be4, m4, v4,
                                    w1b, w4b, bn1s, bn1h, bn2s, bn2h);
    k1_mfma<<<2048, 256, 0, stream>>>(x, w1b, w4b, bn1s, bn1h, bn2s, bn2h, outp);
}

// Round 14
// 154.858 us; speedup vs baseline: 1.2148x; 1.2148x over previous
//
#include <hip/hip_runtime.h>
#include <hip/hip_bf16.h>
#include <math.h>

#define EPS 1e-5f

typedef __attribute__((ext_vector_type(8))) short bf8_t;   // 8 bf16 = MFMA A/B frag
typedef __attribute__((ext_vector_type(4))) float f4_t;    // MFMA C/D frag

static __device__ __forceinline__ unsigned short f2b(float f) {
    __hip_bfloat16 h = __float2bfloat16(f);
    return *reinterpret_cast<unsigned short*>(&h);
}

// ws layout (bytes):
//   0        : W1B  frag-linear bf16 of W123: idx ((mt*16+ks)*64+lane)*8+j  (196608 B)
//   196608   : W4B  frag-linear bf16 of W4:   idx ((mt*2+ks)*64+lane)*8+j   (65536 B)
//   262144   : bn1s[192], 262912: bn1h[192]
//   263680   : bn2s[512], 265728: bn2h[512]

// ---------------- K0: weight conversion to fragment-linear bf16 + BN folds ----------------
__global__ __launch_bounds__(256) void k0_prep(
    const float* __restrict__ W123, const float* __restrict__ W4,
    const float* __restrict__ b123, const float* __restrict__ g123,
    const float* __restrict__ be123, const float* __restrict__ m123, const float* __restrict__ v123,
    const float* __restrict__ b4, const float* __restrict__ g4,
    const float* __restrict__ be4, const float* __restrict__ m4, const float* __restrict__ v4,
    unsigned short* __restrict__ w1b, unsigned short* __restrict__ w4b,
    float* __restrict__ bn1s, float* __restrict__ bn1h,
    float* __restrict__ bn2s, float* __restrict__ bn2h)
{
    const int bid = blockIdx.x, tid = threadIdx.x;
    if (bid == 64) {
        if (tid < 192) {
            float s = g123[tid] * rsqrtf(v123[tid] + EPS);
            bn1s[tid] = s;
            bn1h[tid] = be123[tid] + (b123[tid] - m123[tid]) * s;
        }
        for (int c = tid; c < 512; c += 256) {
            float s = g4[c] * rsqrtf(v4[c] + EPS);
            bn2s[c] = s;
            bn2h[c] = be4[c] + (b4[c] - m4[c]) * s;
        }
        return;
    }
    const int f = bid * 256 + tid;     // 0..16383
    const float* src;
    unsigned short* dst;
    if (f < 12288) {                   // W123 frags: 12 mtiles x 16 ksteps x 64 lanes
        int mt = f >> 10, ks = (f >> 6) & 15, lane = f & 63;
        int row = mt * 16 + (lane & 15);
        int k0  = ks * 32 + ((lane >> 4) << 3);
        src = W123 + row * 512 + k0;
        dst = w1b + f * 8;
    } else {                           // W4 frags: 32 mtiles x 2 ksteps x 64 lanes
        int f2 = f - 12288;
        int mt = f2 >> 7, ks = (f2 >> 6) & 1, lane = f2 & 63;
        int row = mt * 16 + (lane & 15);
        int k0  = ks * 32 + ((lane >> 4) << 3);
        src = W4 + row * 64 + k0;
        dst = w4b + f2 * 8;
    }
    float4 a = *(const float4*)src;
    float4 b = *(const float4*)(src + 4);
    union { unsigned short u[8]; uint4 v; } o;
    o.u[0]=f2b(a.x); o.u[1]=f2b(a.y); o.u[2]=f2b(a.z); o.u[3]=f2b(a.w);
    o.u[4]=f2b(b.x); o.u[5]=f2b(b.y); o.u[6]=f2b(b.z); o.u[7]=f2b(b.w);
    *(uint4*)dst = o.v;
}

// ---------------- K1: 1 sample/block, 2048 blocks x 256 threads (4 waves) ----------------
// x held in registers P1->P5 (no re-read). LDS 8.8KB overlaid. VGPR cap 128 (4 blocks/CU)
// so the GEMM1 ks-loop can keep multiple W-frag loads in flight.
__global__ __launch_bounds__(256, 4) void k1_mfma(
    const float* __restrict__ x,
    const unsigned short* __restrict__ w1b,
    const unsigned short* __restrict__ w4b,
    const float* __restrict__ bn1s, const float* __restrict__ bn1h,
    const float* __restrict__ bn2s, const float* __restrict__ bn2h,
    float* __restrict__ out)
{
    // Union region, 8768 B. Time-disjoint overlays:
    //   Bxs  [4][520] bf16 @ 0     (4160B)  live P1 -> GEMM1
    //   actL [192][5] f32  @ 4160  (3840B)  live GEMM1 -> attention
    //   B2   [4][72]  bf16 @ 0     (576B)   live attn -> GEMM2 (dead Bxs space)
    //   bn2L [2048]   f32  @ 576   (8192B)  live GEMM2-epi -> P5 (no overlap with B2)
    __shared__ __align__(16) char U[8768];

    unsigned short* Bxs  = (unsigned short*)&U[0];      // [p][c] stride 520
    float*          actL = (float*)&U[4160];            // [row][col] stride 5
    unsigned short* B2   = (unsigned short*)&U[0];      // [l][d] stride 72
    float*          bn2L = (float*)&U[576];             // flat [c*4+h]

    const int tid = threadIdx.x;
    const int lane = tid & 63, w = tid >> 6;
    const int n = blockIdx.x;
    const float4* x4 = (const float4*)(x + (size_t)n * 8192);
    float4* o4 = (float4*)(out + (size_t)n * 8192);

    // ---- P1: stream x once into registers; extract bf16 subsample to LDS
    float4 xr[8];
    #pragma unroll
    for (int k = 0; k < 8; ++k) xr[k] = x4[tid + k * 256];

    {
        const int j = tid & 3;             // == h position of this thread's float4s (const over k)
        const int cb = tid >> 2;
        if (j == 0) {
            #pragma unroll
            for (int k = 0; k < 8; ++k) {
                int c = cb + k * 64;
                Bxs[0 * 520 + c] = f2b(xr[k].x);   // (h0,w0)
                Bxs[1 * 520 + c] = f2b(xr[k].z);   // (h0,w2)
            }
        } else if (j == 2) {
            #pragma unroll
            for (int k = 0; k < 8; ++k) {
                int c = cb + k * 64;
                Bxs[2 * 520 + c] = f2b(xr[k].x);   // (h2,w0)
                Bxs[3 * 520 + c] = f2b(xr[k].z);   // (h2,w2)
            }
        }
    }
    __syncthreads();

    // ---- GEMM1: C1(192x4) = W123(192x512) @ XS(512x4); wave w owns mtiles 3w..3w+2
    {
        f4_t acc[3] = {};
        const bf8_t* Af = (const bf8_t*)w1b;
        const int col = lane & 15, kb = (lane >> 4) << 3;
        #pragma unroll 4
        for (int ks = 0; ks < 16; ++ks) {
            bf8_t bf = *(const bf8_t*)&Bxs[(col & 3) * 520 + ks * 32 + kb];
            #pragma unroll
            for (int mi = 0; mi < 3; ++mi) {
                int mt = w * 3 + mi;
                bf8_t af = Af[(mt * 16 + ks) * 64 + lane];
                acc[mi] = __builtin_amdgcn_mfma_f32_16x16x32_bf16(af, bf, acc[mi], 0, 0, 0);
            }
        }
        if (col < 4) {
            #pragma unroll
            for (int mi = 0; mi < 3; ++mi) {
                int rbase = (w * 3 + mi) * 16 + ((lane >> 4) << 2);
                #pragma unroll
                for (int r = 0; r < 4; ++r) {
                    int row = rbase + r;
                    float v = acc[mi][r] * bn1s[row] + bn1h[row];
                    actL[row * 5 + col] = fmaxf(v, 0.f);
                }
            }
        }
    }
    __syncthreads();

    // ---- Attention: wave 0 only, barrier-free (shfl for all cross-lane comms)
    if (tid < 64) {
        // scores: lanes (tid&31): i=(tid&31)>>1 -> (l,m); dg=tid&1 splits d-range
        int i = (tid & 31) >> 1, dg = tid & 1;
        int sl = i >> 2, sm = i & 3;
        float part = 0.f;
        #pragma unroll 8
        for (int kk = 0; kk < 32; ++kk) {
            int d = dg * 32 + kk;
            part += actL[d * 5 + sl] * actL[(64 + d) * 5 + sm];
        }
        part += __shfl_xor(part, 1);       // full dot s[sl][sm] on all lanes

        // each lane gathers the score row it needs for PV: row l2 = tid>>4
        int l2 = tid >> 4, dblk = tid & 15;
        float s0 = __shfl(part, (l2 * 4 + 0) * 2);
        float s1 = __shfl(part, (l2 * 4 + 1) * 2);
        float s2 = __shfl(part, (l2 * 4 + 2) * 2);
        float s3 = __shfl(part, (l2 * 4 + 3) * 2);
        float mx = fmaxf(fmaxf(s0, s1), fmaxf(s2, s3));
        float e0 = expf(s0 - mx), e1 = expf(s1 - mx);
        float e2 = expf(s2 - mx), e3 = expf(s3 - mx);
        float inv = 1.f / (e0 + e1 + e2 + e3);
        float p0 = e0 * inv, p1 = e1 * inv, p2 = e2 * inv, p3 = e3 * inv;

        // PV: lane handles d = dblk*4 .. dblk*4+3 for row l2; write B2[l2][d]
        #pragma unroll
        for (int jj = 0; jj < 4; ++jj) {
            int d = dblk * 4 + jj;
            float sum = p0 * actL[(128 + d) * 5 + 0] + p1 * actL[(128 + d) * 5 + 1]
                      + p2 * actL[(128 + d) * 5 + 2] + p3 * actL[(128 + d) * 5 + 3];
            B2[l2 * 72 + d] = f2b(sum);
        }
    }
    __syncthreads();

    // ---- GEMM2: C2(512x4) = W4(512x64) @ att(64x4); wave w owns mtiles 8w..8w+7
    {
        const bf8_t* A2f = (const bf8_t*)w4b;
        const int col = lane & 15, kb = (lane >> 4) << 3;
        f4_t acc2[8] = {};
        #pragma unroll
        for (int ks = 0; ks < 2; ++ks) {
            bf8_t bf = *(const bf8_t*)&B2[(col & 3) * 72 + ks * 32 + kb];
            #pragma unroll
            for (int mi = 0; mi < 8; ++mi) {
                int mt = w * 8 + mi;
                bf8_t af = A2f[(mt * 2 + ks) * 64 + lane];
                acc2[mi] = __builtin_amdgcn_mfma_f32_16x16x32_bf16(af, bf, acc2[mi], 0, 0, 0);
            }
        }
        // BN2 -> bn2L[c*4 + h=col] (cols 0-3 real); bn2L @576 doesn't overlap live B2 @0..576
        if (col < 4) {
            #pragma unroll
            for (int mi = 0; mi < 8; ++mi) {
                int cbase = (w * 8 + mi) * 16 + ((lane >> 4) << 2);
                #pragma unroll
                for (int r = 0; r < 4; ++r) {
                    int c = cbase + r;
                    bn2L[c * 4 + col] = acc2[mi][r] * bn2s[c] + bn2h[c];
                }
            }
        }
    }
    __syncthreads();

    // ---- P5: out = xr + bn2 — pure store stream (x never re-read)
    #pragma unroll
    for (int k = 0; k < 8; ++k) {
        int f = tid + k * 256;             // f = c*4 + h == flat bn2L index
        float b = bn2L[f];
        o4[f] = make_float4(xr[k].x + b, xr[k].y + b, xr[k].z + b, xr[k].w + b);
    }
}

extern "C" void kernel_launch(void* const* d_in, const int* in_sizes, int n_in,
                              void* d_out, int out_size, void* d_ws, size_t ws_size,
                              hipStream_t stream) {
    const float* x     = (const float*)d_in[0];
    const float* W123  = (const float*)d_in[1];
    const float* b123  = (const float*)d_in[2];
    const float* g123  = (const float*)d_in[3];
    const float* be123 = (const float*)d_in[4];
    const float* m123  = (const float*)d_in[5];
    const float* v123  = (const float*)d_in[6];
    const float* W4    = (const float*)d_in[7];
    const float* b4    = (const float*)d_in[8];
    const float* g4    = (const float*)d_in[9];
    const float* be4   = (const float*)d_in[10];
    const float* m4    = (const float*)d_in[11];
    const float* v4    = (const float*)d_in[12];
    float* outp = (float*)d_out;

    char* ws = (char*)d_ws;
    unsigned short* w1b = (unsigned short*)ws;
    unsigned short* w4b = (unsigned short*)(ws + 196608);
    float* bn1s = (float*)(ws + 262144);
    float* bn1h = (float*)(ws + 262912);
    float* bn2s = (float*)(ws + 263680);
    float* bn2h = (float*)(ws + 265728);

    k0_prep<<<65, 256, 0, stream>>>(W123, W4, b123, g123, be123, m123, v123,
                                    b4, g4, be4, m4, v4,
                                    w1b, w4b, bn1s, bn1h, bn2s, bn2h);
    k1_mfma<<<2048, 256, 0, stream>>>(x, w1b, w4b, bn1s, bn1h, bn2s, bn2h, outp);
}

// Round 15
// 154.828 us; speedup vs baseline: 1.2150x; 1.0002x over previous
//
#include <hip/hip_runtime.h>
#include <hip/hip_bf16.h>
#include <math.h>

#define EPS 1e-5f

typedef __attribute__((ext_vector_type(8))) short bf8_t;   // 8 bf16 = MFMA A/B frag
typedef __attribute__((ext_vector_type(4))) float f4_t;    // MFMA C/D frag

static __device__ __forceinline__ unsigned short f2b(float f) {
    __hip_bfloat16 h = __float2bfloat16(f);
    return *reinterpret_cast<unsigned short*>(&h);
}

// ws layout (bytes):
//   0        : W1B  frag-linear bf16 of W123: idx ((mt*16+ks)*64+lane)*8+j  (196608 B)
//   196608   : W4B  frag-linear bf16 of W4:   idx ((mt*2+ks)*64+lane)*8+j   (65536 B)
//   262144   : bn1s[192], 262912: bn1h[192]
//   263680   : bn2s[512], 265728: bn2h[512]
//   524288   : attg[2048*256] bf16 (1 MB)  — attention output, [n][l*64+d]

// ---------------- K0: weight conversion to fragment-linear bf16 + BN folds ----------------
__global__ __launch_bounds__(256) void k0_prep(
    const float* __restrict__ W123, const float* __restrict__ W4,
    const float* __restrict__ b123, const float* __restrict__ g123,
    const float* __restrict__ be123, const float* __restrict__ m123, const float* __restrict__ v123,
    const float* __restrict__ b4, const float* __restrict__ g4,
    const float* __restrict__ be4, const float* __restrict__ m4, const float* __restrict__ v4,
    unsigned short* __restrict__ w1b, unsigned short* __restrict__ w4b,
    float* __restrict__ bn1s, float* __restrict__ bn1h,
    float* __restrict__ bn2s, float* __restrict__ bn2h)
{
    const int bid = blockIdx.x, tid = threadIdx.x;
    if (bid == 64) {
        if (tid < 192) {
            float s = g123[tid] * rsqrtf(v123[tid] + EPS);
            bn1s[tid] = s;
            bn1h[tid] = be123[tid] + (b123[tid] - m123[tid]) * s;
        }
        for (int c = tid; c < 512; c += 256) {
            float s = g4[c] * rsqrtf(v4[c] + EPS);
            bn2s[c] = s;
            bn2h[c] = be4[c] + (b4[c] - m4[c]) * s;
        }
        return;
    }
    const int f = bid * 256 + tid;     // 0..16383
    const float* src;
    unsigned short* dst;
    if (f < 12288) {                   // W123 frags: 12 mtiles x 16 ksteps x 64 lanes
        int mt = f >> 10, ks = (f >> 6) & 15, lane = f & 63;
        int row = mt * 16 + (lane & 15);
        int k0  = ks * 32 + ((lane >> 4) << 3);
        src = W123 + row * 512 + k0;
        dst = w1b + f * 8;
    } else {                           // W4 frags: 32 mtiles x 2 ksteps x 64 lanes
        int f2 = f - 12288;
        int mt = f2 >> 7, ks = (f2 >> 6) & 1, lane = f2 & 63;
        int row = mt * 16 + (lane & 15);
        int k0  = ks * 32 + ((lane >> 4) << 3);
        src = W4 + row * 64 + k0;
        dst = w4b + f2 * 8;
    }
    float4 a = *(const float4*)src;
    float4 b = *(const float4*)(src + 4);
    union { unsigned short u[8]; uint4 v; } o;
    o.u[0]=f2b(a.x); o.u[1]=f2b(a.y); o.u[2]=f2b(a.z); o.u[3]=f2b(a.w);
    o.u[4]=f2b(b.x); o.u[5]=f2b(b.y); o.u[6]=f2b(b.z); o.u[7]=f2b(b.w);
    *(uint4*)dst = o.v;
}

// ---------------- K1: gather + GEMM1 + BN/ReLU + attention -> attg (bf16) ----------------
// 4 samples/block (16 MFMA cols), 512 blocks x 256 threads (4 waves).
__global__ __launch_bounds__(256) void k1_att(
    const float* __restrict__ x,
    const unsigned short* __restrict__ w1b,
    const float* __restrict__ bn1s, const float* __restrict__ bn1h,
    unsigned short* __restrict__ attg)
{
    __shared__ unsigned short Bxs[16][536];  // [col=s*4+p][k=c]
    __shared__ float actL[192][17];          // [kd][col] post BN+ReLU
    __shared__ float smx[4][17];             // per-sample scores -> probs

    const int tid = threadIdx.x;
    const int lane = tid & 63, w = tid >> 6;
    const int n0 = blockIdx.x * 4;

    // ---- P1: gather xs (4 samples): hoist all 16 HBM loads, then convert+stage
    float4 xa[8], xb[8];
    #pragma unroll
    for (int it = 0; it < 8; ++it) {
        int i = it * 256 + tid;            // i = s*512 + c
        const float* xp = x + (size_t)(n0 + (i >> 9)) * 8192 + (i & 511) * 16;
        xa[it] = *(const float4*)xp;       // h=0: w=0 -> .x, w=2 -> .z
        xb[it] = *(const float4*)(xp + 8); // h=2: w=0 -> .x, w=2 -> .z
    }
    #pragma unroll
    for (int it = 0; it < 8; ++it) {
        int i = it * 256 + tid;
        int s = i >> 9, c = i & 511;
        Bxs[s * 4 + 0][c] = f2b(xa[it].x);
        Bxs[s * 4 + 1][c] = f2b(xa[it].z);
        Bxs[s * 4 + 2][c] = f2b(xb[it].x);
        Bxs[s * 4 + 3][c] = f2b(xb[it].z);
    }
    __syncthreads();

    // ---- GEMM1: C1(192x16) = W123(192x512) @ XS(512x16); wave w owns mtiles 3w..3w+2
    // depth-2 software prefetch of A-fragments (rotating afp[ks%3], fully unrolled)
    {
        f4_t acc[3] = {};
        const bf8_t* Af = (const bf8_t*)w1b;
        const int col = lane & 15, kg = (lane >> 4) << 3;
        bf8_t afp[3][3];
        #pragma unroll
        for (int mi = 0; mi < 3; ++mi) {
            afp[0][mi] = Af[((w * 3 + mi) * 16 + 0) * 64 + lane];
            afp[1][mi] = Af[((w * 3 + mi) * 16 + 1) * 64 + lane];
        }
        #pragma unroll
        for (int ks = 0; ks < 16; ++ks) {
            if (ks < 14) {
                #pragma unroll
                for (int mi = 0; mi < 3; ++mi)
                    afp[(ks + 2) % 3][mi] = Af[((w * 3 + mi) * 16 + ks + 2) * 64 + lane];
            }
            bf8_t bf = *(const bf8_t*)&Bxs[col][ks * 32 + kg];
            #pragma unroll
            for (int mi = 0; mi < 3; ++mi)
                acc[mi] = __builtin_amdgcn_mfma_f32_16x16x32_bf16(afp[ks % 3][mi], bf, acc[mi], 0, 0, 0);
        }
        #pragma unroll
        for (int mi = 0; mi < 3; ++mi) {
            int rbase = (w * 3 + mi) * 16 + ((lane >> 4) << 2);
            #pragma unroll
            for (int r = 0; r < 4; ++r) {
                int row = rbase + r;
                float v = acc[mi][r] * bn1s[row] + bn1h[row];
                actL[row][col] = fmaxf(v, 0.f);
            }
        }
    }
    __syncthreads();

    // ---- scores[s][l][m] = sum_d q[d][l]*k[d][m]  (threads 0..127; 2 lanes per dot)
    if (tid < 128) {
        int s = tid >> 5, l = (tid >> 3) & 3, m = (tid >> 1) & 3, dg = tid & 1;
        float part = 0.f;
        #pragma unroll 8
        for (int k = 0; k < 32; ++k) {
            int d = dg * 32 + k;
            part += actL[d][s * 4 + l] * actL[64 + d][s * 4 + m];
        }
        part += __shfl_xor(part, 1);
        if (dg == 0) smx[s][l * 4 + m] = part;
    }
    __syncthreads();

    // ---- softmax rows (threads 0..15)
    if (tid < 16) {
        int s = tid >> 2, l = tid & 3;
        float s0 = smx[s][l*4+0], s1 = smx[s][l*4+1], s2 = smx[s][l*4+2], s3 = smx[s][l*4+3];
        float mx = fmaxf(fmaxf(s0, s1), fmaxf(s2, s3));
        float e0 = expf(s0-mx), e1 = expf(s1-mx), e2 = expf(s2-mx), e3 = expf(s3-mx);
        float inv = 1.f / (e0 + e1 + e2 + e3);
        smx[s][l*4+0] = e0*inv; smx[s][l*4+1] = e1*inv;
        smx[s][l*4+2] = e2*inv; smx[s][l*4+3] = e3*inv;
    }
    __syncthreads();

    // ---- PV: att[s][l][d] = sum_m p[l][m]*v[d][m] -> attg bf16 (packed 16B stores)
    if (tid < 128) {
        int s = tid >> 5, l = (tid >> 3) & 3, d0 = (tid & 7) * 8;
        float p0 = smx[s][l*4+0], p1 = smx[s][l*4+1], p2 = smx[s][l*4+2], p3 = smx[s][l*4+3];
        union { unsigned short u[8]; uint4 v; } o;
        #pragma unroll
        for (int j = 0; j < 8; ++j) {
            int d = d0 + j;
            float sum = p0 * actL[128+d][s*4+0] + p1 * actL[128+d][s*4+1]
                      + p2 * actL[128+d][s*4+2] + p3 * actL[128+d][s*4+3];
            o.u[j] = f2b(sum);
        }
        *(uint4*)&attg[(size_t)(n0 + s) * 256 + l * 64 + d0] = o.v;
    }
}

// ---------------- K2: GEMM2 + BN2 + residual stream ----------------
// 1 sample/block, 2048 blocks x 256 threads. x loads issued FIRST (consumed last).
__global__ __launch_bounds__(256) void k2_out(
    const float* __restrict__ x,
    const unsigned short* __restrict__ attg,
    const unsigned short* __restrict__ w4b,
    const float* __restrict__ bn2s, const float* __restrict__ bn2h,
    float* __restrict__ out)
{
    __shared__ unsigned short B2[4][72];     // att [l][d] (stride 72, rows 16B-aligned)
    __shared__ float bn2L[2048];             // bn2 flat [c*4+h]

    const int tid = threadIdx.x;
    const int lane = tid & 63, w = tid >> 6;
    const int n = blockIdx.x;
    const float4* x4 = (const float4*)(x + (size_t)n * 8192);
    float4* o4 = (float4*)(out + (size_t)n * 8192);

    // ---- issue x loads first; consumed after GEMM2 (latency hides under compute)
    float4 xr[8];
    #pragma unroll
    for (int k = 0; k < 8; ++k) xr[k] = x4[tid + k * 256];

    // ---- stage att row into LDS (32 threads x 16B)
    if (tid < 32) {
        uint4 v = *(const uint4*)&attg[(size_t)n * 256 + tid * 8];
        int l = tid >> 3, d0 = (tid & 7) * 8;
        *(uint4*)&B2[l][d0] = v;
    }
    __syncthreads();

    // ---- GEMM2: C2(512x4) = W4(512x64) @ att(64x4); wave w owns mtiles 8w..8w+7
    {
        const bf8_t* A2f = (const bf8_t*)w4b;
        const int col = lane & 15, kb = (lane >> 4) << 3;
        f4_t acc2[8] = {};
        #pragma unroll
        for (int ks = 0; ks < 2; ++ks) {
            bf8_t bf = *(const bf8_t*)&B2[col & 3][ks * 32 + kb];
            #pragma unroll
            for (int mi = 0; mi < 8; ++mi) {
                int mt = w * 8 + mi;
                bf8_t af = A2f[(mt * 2 + ks) * 64 + lane];
                acc2[mi] = __builtin_amdgcn_mfma_f32_16x16x32_bf16(af, bf, acc2[mi], 0, 0, 0);
            }
        }
        if (col < 4) {
            #pragma unroll
            for (int mi = 0; mi < 8; ++mi) {
                int cbase = (w * 8 + mi) * 16 + ((lane >> 4) << 2);
                #pragma unroll
                for (int r = 0; r < 4; ++r) {
                    int c = cbase + r;
                    bn2L[c * 4 + col] = acc2[mi][r] * bn2s[c] + bn2h[c];
                }
            }
        }
    }
    __syncthreads();

    // ---- residual: out = xr + bn2 (broadcast over w)
    #pragma unroll
    for (int k = 0; k < 8; ++k) {
        int f = tid + k * 256;             // f = c*4 + h == flat bn2L index
        float b = bn2L[f];
        o4[f] = make_float4(xr[k].x + b, xr[k].y + b, xr[k].z + b, xr[k].w + b);
    }
}

extern "C" void kernel_launch(void* const* d_in, const int* in_sizes, int n_in,
                              void* d_out, int out_size, void* d_ws, size_t ws_size,
                              hipStream_t stream) {
    const float* x     = (const float*)d_in[0];
    const float* W123  = (const float*)d_in[1];
    const float* b123  = (const float*)d_in[2];
    const float* g123  = (const float*)d_in[3];
    const float* be123 = (const float*)d_in[4];
    const float* m123  = (const float*)d_in[5];
    const float* v123  = (const float*)d_in[6];
    const float* W4    = (const float*)d_in[7];
    const float* b4    = (const float*)d_in[8];
    const float* g4    = (const float*)d_in[9];
    const float* be4   = (const float*)d_in[10];
    const float* m4    = (const float*)d_in[11];
    const float* v4    = (const float*)d_in[12];
    float* outp = (float*)d_out;

    char* ws = (char*)d_ws;
    unsigned short* w1b = (unsigned short*)ws;
    unsigned short* w4b = (unsigned short*)(ws + 196608);
    float* bn1s = (float*)(ws + 262144);
    float* bn1h = (float*)(ws + 262912);
    float* bn2s = (float*)(ws + 263680);
    float* bn2h = (float*)(ws + 265728);
    unsigned short* attg = (unsigned short*)(ws + 524288);   // 1 MB

    k0_prep<<<65, 256, 0, stream>>>(W123, W4, b123, g123, be123, m123, v123,
                                    b4, g4, be4, m4, v4,
                                    w1b, w4b, bn1s, bn1h, bn2s, bn2h);
    k1_att<<<512, 256, 0, stream>>>(x, w1b, bn1s, bn1h, attg);
    k2_out<<<2048, 256, 0, stream>>>(x, attg, w4b, bn2s, bn2h, outp);
}